// Round 6
// baseline (172.897 us; speedup 1.0000x reference)
//
#include <hip/hip_runtime.h>

typedef __bf16 bf16;
typedef __bf16 bf16x4 __attribute__((ext_vector_type(4)));
typedef __bf16 bf16x8 __attribute__((ext_vector_type(8)));
typedef float  f32x4  __attribute__((ext_vector_type(4)));

#define HH 256
#define WW 256
#define NB 2
#define NC 64
#define NS 65536
#define EX 258      // extended conv grid: real coords -1..256, stored +1
#define NHEAD 4
#define DH 16
#define NSTRIPE 8
#define ACCSZ 2304  // per stripe: dots 2048 + qss 128 + kss 128

// ws layout (bytes)
#define OFF_CEXT   0ul                 // 2*258*258*64*2 = 17040384
#define OFF_KV     17040384ul          // kvT [b][s][c] bf16: 2*65536*64*2 = 16777216
#define OFF_WPK    33817600ul          // 73728
#define OFF_ACC    33891328ul          // 8*2304*4 = 73728
#define OFF_ATTN   33965056ul          // 2*1024*4 = 8192

// ---------------- K0w: pack weights to A-frag layout + zero accums ---------
__global__ void k0w(const float* __restrict__ wgt, bf16* __restrict__ wpk,
                    float* __restrict__ accums) {
    int t = blockIdx.x * 256 + threadIdx.x;
    if (t < 9 * 2 * 4 * 64) {
        int L   = t & 63;
        int mtg = (t >> 6) & 3;
        int kc  = (t >> 8) & 1;
        int tap = t >> 9;
        int o  = mtg * 16 + (L & 15);
        int cb = kc * 32 + (L >> 4) * 8;
        bf16x8 vv;
        #pragma unroll
        for (int j = 0; j < 8; j++)
            vv[j] = (bf16)wgt[(o * 64 + (cb + j)) * 9 + tap];
        *(bf16x8*)(wpk + t * 8) = vv;
    }
    int z = t - 9 * 2 * 4 * 64;
    if (z >= 0 && z < NSTRIPE * ACCSZ) accums[z] = 0.0f;
}

// ---------------- K1: 3x3 conv, staging straight from f32 clone ------------
__global__ __launch_bounds__(256, 2) void k1_conv(const float* __restrict__ clone,
                                                  const bf16* __restrict__ wpk,
                                                  bf16* __restrict__ cext) {
    const int Xt = blockIdx.x;   // 0..4
    const int Yt = blockIdx.y;   // 0..42  (43*6 = 258 exactly)
    const int b  = blockIdx.z;
    const int t  = threadIdx.x;
    const int L  = t & 63;
    const int wv = t >> 6;
    const int mpair = wv >> 1;
    const int npair = wv & 1;

    extern __shared__ bf16 tile[];       // [8 rows][68 cols][c pitch 72]

    bf16x8 afrag[2][9][2];
    #pragma unroll
    for (int mt = 0; mt < 2; mt++)
        #pragma unroll
        for (int tap = 0; tap < 9; tap++)
            #pragma unroll
            for (int kc = 0; kc < 2; kc++) {
                int idx = ((tap * 2 + kc) * 4 + (mpair * 2 + mt)) * 64 + L;
                afrag[mt][tap][kc] = *(const bf16x8*)(wpk + idx * 8);
            }

    for (int u = t; u < 2176; u += 256) {
        int xq = u % 17;
        int rc = u / 17;
        int cg = rc & 15;
        int r  = rc >> 4;
        int y  = Yt * 6 - 2 + r;
        int xg0 = Xt * 64 - 4 + xq * 4;
        int c0 = cg * 4;
        f32x4 f[4];
        bool yin = (y >= 0) && (y < HH);
        if (yin && xg0 >= 0 && xg0 + 3 < WW) {
            #pragma unroll
            for (int i = 0; i < 4; i++)
                f[i] = *(const f32x4*)(clone + ((size_t)(b * NC + c0 + i) * HH + y) * WW + xg0);
        } else {
            #pragma unroll
            for (int i = 0; i < 4; i++)
                #pragma unroll
                for (int e = 0; e < 4; e++) {
                    int xg = xg0 + e;
                    f[i][e] = (yin && xg >= 0 && xg < WW)
                            ? clone[((size_t)(b * NC + c0 + i) * HH + y) * WW + xg] : 0.0f;
                }
        }
        #pragma unroll
        for (int e = 0; e < 4; e++) {
            bf16x4 h;
            #pragma unroll
            for (int i = 0; i < 4; i++) h[i] = (bf16)f[i][e];
            *(bf16x4*)(tile + (r * 68 + xq * 4 + e) * 72 + c0) = h;
        }
    }
    __syncthreads();

    const int nbase = Xt * 64 + npair * 32;
    const f32x4 zero4 = {0.0f, 0.0f, 0.0f, 0.0f};
    for (int Yi = 0; Yi < 6; Yi++) {
        f32x4 acc[2][2];
        acc[0][0] = zero4; acc[0][1] = zero4; acc[1][0] = zero4; acc[1][1] = zero4;
        #pragma unroll
        for (int tap = 0; tap < 9; tap++) {
            const int ky = tap / 3 - 1;
            const int kx = tap % 3 - 1;
            const int r = Yi + 1 + ky;
            #pragma unroll
            for (int kc = 0; kc < 2; kc++) {
                const int cb = kc * 32 + (L >> 4) * 8;
                #pragma unroll
                for (int nt = 0; nt < 2; nt++) {
                    if (nbase + nt * 16 < EX) {   // wave-uniform skip of dead N-tiles
                        const int col = npair * 32 + nt * 16 + (L & 15) + kx + 3;
                        bf16x8 bfrag = *(const bf16x8*)(tile + (r * 68 + col) * 72 + cb);
                        #pragma unroll
                        for (int mt = 0; mt < 2; mt++)
                            acc[mt][nt] = __builtin_amdgcn_mfma_f32_16x16x32_bf16(
                                afrag[mt][tap][kc], bfrag, acc[mt][nt], 0, 0, 0);
                    }
                }
            }
        }
        int Yp = Yt * 6 + Yi;
        #pragma unroll
        for (int mt = 0; mt < 2; mt++)
            #pragma unroll
            for (int nt = 0; nt < 2; nt++) {
                int Xp = Xt * 64 + npair * 32 + nt * 16 + (L & 15);
                if (Xp < EX) {
                    int o = mpair * 32 + mt * 16 + (L >> 4) * 4;
                    bf16x4 st;
                    #pragma unroll
                    for (int rg = 0; rg < 4; rg++) st[rg] = (bf16)acc[mt][nt][rg];
                    *(bf16x4*)(cext + ((((size_t)b * EX + Yp) * EX + Xp) << 6) + o) = st;
                }
            }
    }
}

// ---------------- K2: fused gather + dots (kvT dense stores) ---------------
__global__ __launch_bounds__(256) void k2_gd(const float* __restrict__ uu,
                                             const float* __restrict__ vv,
                                             const float* __restrict__ x,
                                             const bf16* __restrict__ cext,
                                             bf16* __restrict__ kvT,
                                             float* __restrict__ accums) {
    const int bx = blockIdx.x;                    // 0..511
    const int b  = blockIdx.z;
    const int strip = (bx & 7) * 64 + (bx >> 3);  // bijective (512 % 8 == 0)
    const int t = threadIdx.x;
    const int px = t >> 1;
    const int half = t & 1;
    const int hw = strip * 128 + px;
    const int idx = b * NS + hw;
    const int hy = hw >> 8;
    const int wx = hw & 255;

    __shared__ bf16 tile[128][68];                // [s_local][ch], pitch 68

    // ---- gather phase ----
    float fv = vv[idx];
    float fu = uu[idx];
    float py_f = (float)hy + fv;
    float px_f = (float)wx + fu;
    float fy = floorf(py_f);
    float fx = floorf(px_f);
    float ay = py_f - fy;
    float ax = px_f - fx;
    int ys = (int)fy + 1;
    int xs = (int)fx + 1;
    float w00 = (1.0f - ay) * (1.0f - ax);
    float w01 = (1.0f - ay) * ax;
    float w10 = ay * (1.0f - ax);
    float w11 = ay * ax;
    bool y0i = (ys >= 0) && (ys < EX);
    bool y1i = (ys + 1 >= 0) && (ys + 1 < EX);
    bool x0i = (xs >= 0) && (xs < EX);
    bool x1i = (xs + 1 >= 0) && (xs + 1 < EX);
    if (!y0i) { w00 = 0.0f; w01 = 0.0f; }
    if (!y1i) { w10 = 0.0f; w11 = 0.0f; }
    if (!x0i) { w00 = 0.0f; w10 = 0.0f; }
    if (!x1i) { w01 = 0.0f; w11 = 0.0f; }
    int y0c = ys < 0 ? 0 : (ys > EX - 1 ? EX - 1 : ys);
    int y1c = ys + 1 < 0 ? 0 : (ys + 1 > EX - 1 ? EX - 1 : ys + 1);
    int x0c = xs < 0 ? 0 : (xs > EX - 1 ? EX - 1 : xs);
    int x1c = xs + 1 < 0 ? 0 : (xs + 1 > EX - 1 ? EX - 1 : xs + 1);
    const bf16* pb = cext + (((size_t)b * EX * EX) << 6);
    size_t i00 = ((size_t)(y0c * EX + x0c)) << 6;
    size_t i01 = ((size_t)(y0c * EX + x1c)) << 6;
    size_t i10 = ((size_t)(y1c * EX + x0c)) << 6;
    size_t i11 = ((size_t)(y1c * EX + x1c)) << 6;
    const int c0 = half * 32;
    bf16* kvp = kvT + ((size_t)(b * NS + hw)) * 64 + c0;   // 16B-aligned
    #pragma unroll
    for (int g = 0; g < 4; g++) {
        int cg = c0 + g * 8;
        bf16x8 c00 = *(const bf16x8*)(pb + i00 + cg);
        bf16x8 c01 = *(const bf16x8*)(pb + i01 + cg);
        bf16x8 c10 = *(const bf16x8*)(pb + i10 + cg);
        bf16x8 c11 = *(const bf16x8*)(pb + i11 + cg);
        bf16x4 lo, hi;
        bf16x8 sv;
        #pragma unroll
        for (int j = 0; j < 8; j++) {
            float val = w00 * (float)c00[j] + w01 * (float)c01[j]
                      + w10 * (float)c10[j] + w11 * (float)c11[j];
            bf16 hv = (bf16)val;
            sv[j] = hv;
            if (j < 4) lo[j] = hv; else hi[j - 4] = hv;
        }
        *(bf16x8*)(kvp + g * 8) = sv;                      // dense 16B store
        *(bf16x4*)(&tile[px][cg])     = lo;
        *(bf16x4*)(&tile[px][cg + 4]) = hi;
    }
    __syncthreads();

    // ---- dots phase: wave = head ----
    const int L  = t & 63;
    const int h  = t >> 6;
    const int row = L & 15;
    const int kg  = L >> 4;
    const int bh = b * NHEAD + h;
    const float* qb = x + ((size_t)(b * NC + h * DH + row)) * NS + strip * 128;
    f32x4 acc = {0.0f, 0.0f, 0.0f, 0.0f};
    float qp = 0.0f, kp = 0.0f;
    #pragma unroll
    for (int it = 0; it < 4; it++) {
        const int s = it * 32 + kg * 8;
        f32x4 q0 = *(const f32x4*)(qb + s);
        f32x4 q1 = *(const f32x4*)(qb + s + 4);
        bf16x8 qa, ka;
        #pragma unroll
        for (int j = 0; j < 4; j++) {
            qa[j]     = (bf16)q0[j];
            qa[j + 4] = (bf16)q1[j];
        }
        #pragma unroll
        for (int j = 0; j < 8; j++) ka[j] = tile[s + j][h * DH + row];
        qp += q0[0]*q0[0] + q0[1]*q0[1] + q0[2]*q0[2] + q0[3]*q0[3]
            + q1[0]*q1[0] + q1[1]*q1[1] + q1[2]*q1[2] + q1[3]*q1[3];
        #pragma unroll
        for (int j = 0; j < 8; j++) {
            float kf = (float)ka[j];
            kp += kf * kf;
        }
        acc = __builtin_amdgcn_mfma_f32_16x16x32_bf16(qa, ka, acc, 0, 0, 0);
    }
    float* astripe = accums + (bx & 7) * ACCSZ;
    #pragma unroll
    for (int rg = 0; rg < 4; rg++)
        atomicAdd(astripe + bh * 256 + (kg * 4 + rg) * 16 + row, acc[rg]);
    qp += __shfl_xor(qp, 16); qp += __shfl_xor(qp, 32);
    kp += __shfl_xor(kp, 16); kp += __shfl_xor(kp, 32);
    if (kg == 0) {
        atomicAdd(astripe + 2048 + bh * 16 + row, qp);
        atomicAdd(astripe + 2176 + bh * 16 + row, kp);
    }
}

// ---------------- K4: softmax ONCE -> attnG[b][h][k=j][q=i] (8 KB) ---------
__global__ __launch_bounds__(256) void k4_attn(const float* __restrict__ accums,
                                               const float* __restrict__ temp,
                                               float* __restrict__ attnG) {
    const int b = blockIdx.z;
    const int t = threadIdx.x;
    __shared__ float attn[NHEAD * 256];
    const int i = t >> 4, j = t & 15;
    float lv[4], mx[4], sm[4];
    #pragma unroll
    for (int h = 0; h < NHEAD; h++) {
        const int bh = b * NHEAD + h;
        float dsum = 0.0f, q2 = 0.0f, k2v = 0.0f;
        #pragma unroll
        for (int st = 0; st < NSTRIPE; st++) {
            dsum += accums[st * ACCSZ + bh * 256 + t];
            q2   += accums[st * ACCSZ + 2048 + bh * 16 + i];
            k2v  += accums[st * ACCSZ + 2176 + bh * 16 + j];
        }
        float qn = fmaxf(sqrtf(q2), 1e-12f);
        float kn = fmaxf(sqrtf(k2v), 1e-12f);
        lv[h] = dsum / (qn * kn) * temp[h];
        attn[(h * 16 + j) * 16 + i] = lv[h];
    }
    __syncthreads();
    #pragma unroll
    for (int h = 0; h < NHEAD; h++) {
        float m = -1e30f;
        #pragma unroll
        for (int jj = 0; jj < 16; jj++) m = fmaxf(m, attn[(h * 16 + jj) * 16 + i]);
        float s = 0.0f;
        #pragma unroll
        for (int jj = 0; jj < 16; jj++) s += expf(attn[(h * 16 + jj) * 16 + i] - m);
        mx[h] = m; sm[h] = s;
    }
    __syncthreads();
    #pragma unroll
    for (int h = 0; h < NHEAD; h++)
        attn[(h * 16 + j) * 16 + i] = expf(lv[h] - mx[h]) / sm[h];
    __syncthreads();
    ((f32x4*)(attnG + b * 1024))[t] = ((const f32x4*)attn)[t];
}

// ---------------- K5: out = attn @ kv (attn precomputed) -------------------
// Thread = 1 px x 32 ch: dense 64 B kvT read (full 128 B line used per lane
// pair), FMA into 32 outs, XOR-swizzled oT transpose (read quads spread
// across banks; write side unchanged: key = px>>5 is wave-uniform),
// contiguous 128 B out stores per thread.
__global__ __launch_bounds__(256) void k5_out(const bf16* __restrict__ kvT,
                                              const float* __restrict__ attnG,
                                              float* __restrict__ out) {
    const int bx = blockIdx.x;                    // 0..511
    const int b  = blockIdx.z;
    const int strip = (bx & 7) * 64 + (bx >> 3);
    const int t = threadIdx.x;

    __shared__ float attn[NHEAD * 256];           // [h][k=j][q=i] transposed
    __shared__ float oT[128 * 68];                // [px][c^((px>>5)<<3)]

    ((f32x4*)attn)[t] = ((const f32x4*)(attnG + b * 1024))[t];
    __syncthreads();

    // ---- out = attn @ kv (px-major) ----
    {
        const int px = t >> 1;
        const int half = t & 1;
        const int c0 = half * 32;
        const int h0 = half * 2;
        const int hw = strip * 128 + px;
        const bf16* kr = kvT + ((size_t)(b * NS + hw)) * 64 + c0;
        float kf[32];
        #pragma unroll
        for (int g = 0; g < 4; g++) {
            bf16x8 kk = *(const bf16x8*)(kr + g * 8);
            #pragma unroll
            for (int j = 0; j < 8; j++) kf[g * 8 + j] = (float)kk[j];
        }
        f32x4 acc[8];
        #pragma unroll
        for (int q = 0; q < 8; q++) acc[q] = (f32x4){0.0f, 0.0f, 0.0f, 0.0f};
        #pragma unroll
        for (int hh = 0; hh < 2; hh++)
            #pragma unroll
            for (int j = 0; j < 16; j++) {
                const float kvv = kf[hh * 16 + j];
                const float* ab = &attn[((h0 + hh) * 16 + j) * 16];
                #pragma unroll
                for (int q = 0; q < 4; q++)
                    acc[hh * 4 + q] += *(const f32x4*)(ab + q * 4) * kvv;
            }
        const int key = (px >> 5) << 3;           // wave-uniform on writes
        #pragma unroll
        for (int hh = 0; hh < 2; hh++)
            #pragma unroll
            for (int q = 0; q < 4; q++)
                *(f32x4*)(&oT[px * 68 + ((c0 + hh * 16 + q * 4) ^ key)]) = acc[hh * 4 + q];
    }
    __syncthreads();

    // ---- transpose store, s-contiguous (128 B per thread) ----
    {
        const int c  = t >> 2;
        const int sq = t & 3;
        const int ck = c ^ (sq << 3);             // read-side un-swizzle (row>>5 == sq)
        float* op = out + (((size_t)(b * NC + c)) << 16) + strip * 128 + sq * 32;
        #pragma unroll
        for (int e = 0; e < 8; e++) {
            f32x4 ov;
            #pragma unroll
            for (int k = 0; k < 4; k++) ov[k] = oT[(sq * 32 + e * 4 + k) * 68 + ck];
            *(f32x4*)(op + e * 4) = ov;
        }
    }
}

extern "C" void kernel_launch(void* const* d_in, const int* in_sizes, int n_in,
                              void* d_out, int out_size, void* d_ws, size_t ws_size,
                              hipStream_t stream) {
    const float* clone = (const float*)d_in[0];
    const float* x     = (const float*)d_in[1];
    const float* u     = (const float*)d_in[2];
    const float* v     = (const float*)d_in[3];
    const float* wgt   = (const float*)d_in[4];
    const float* temp  = (const float*)d_in[5];
    float* out = (float*)d_out;

    char* ws = (char*)d_ws;
    bf16*  cext   = (bf16*) (ws + OFF_CEXT);
    bf16*  kvT    = (bf16*) (ws + OFF_KV);
    bf16*  wpk    = (bf16*) (ws + OFF_WPK);
    float* accums = (float*)(ws + OFF_ACC);
    float* attnG  = (float*)(ws + OFF_ATTN);

    static bool attr_set = false;
    if (!attr_set) {
        hipFuncSetAttribute((const void*)k1_conv,
                            hipFuncAttributeMaxDynamicSharedMemorySize, 78336);
        attr_set = true;
    }

    k0w<<<90, 256, 0, stream>>>(wgt, wpk, accums);
    k1_conv<<<dim3(5, 43, 2), 256, 78336, stream>>>(clone, wpk, cext);
    k2_gd<<<dim3(512, 1, 2), 256, 0, stream>>>(u, v, x, cext, kvT, accums);
    k4_attn<<<dim3(1, 1, 2), 256, 0, stream>>>(accums, temp, attnG);
    k5_out<<<dim3(512, 1, 2), 256, 0, stream>>>(kvT, attnG, out);
}

// Round 7
// 157.867 us; speedup vs baseline: 1.0952x; 1.0952x over previous
//
#include <hip/hip_runtime.h>

typedef __bf16 bf16;
typedef __bf16 bf16x4 __attribute__((ext_vector_type(4)));
typedef __bf16 bf16x8 __attribute__((ext_vector_type(8)));
typedef float  f32x4  __attribute__((ext_vector_type(4)));

#define HH 256
#define WW 256
#define NB 2
#define NC 64
#define NS 65536
#define EX 258      // extended conv grid: real coords -1..256, stored +1
#define NHEAD 4
#define DH 16
#define NSTRIPE 8
#define ACCSZ 2304  // per stripe: dots 2048 + qss 128 + kss 128

// ws layout (bytes)
#define OFF_CEXT   0ul                 // 2*258*258*64*2 = 17040384
#define OFF_KV     17040384ul          // kvT [b][s][c] bf16: 2*65536*64*2 = 16777216
#define OFF_WPK    33817600ul          // 73728
#define OFF_ACC    33891328ul          // 8*2304*4 = 73728

// ---------------- K0w: pack weights to A-frag layout + zero accums ---------
__global__ void k0w(const float* __restrict__ wgt, bf16* __restrict__ wpk,
                    float* __restrict__ accums) {
    int t = blockIdx.x * 256 + threadIdx.x;
    if (t < 9 * 2 * 4 * 64) {
        int L   = t & 63;
        int mtg = (t >> 6) & 3;
        int kc  = (t >> 8) & 1;
        int tap = t >> 9;
        int o  = mtg * 16 + (L & 15);
        int cb = kc * 32 + (L >> 4) * 8;
        bf16x8 vv;
        #pragma unroll
        for (int j = 0; j < 8; j++)
            vv[j] = (bf16)wgt[(o * 64 + (cb + j)) * 9 + tap];
        *(bf16x8*)(wpk + t * 8) = vv;
    }
    int z = t - 9 * 2 * 4 * 64;
    if (z >= 0 && z < NSTRIPE * ACCSZ) accums[z] = 0.0f;
}

// ---------------- K1: 3x3 conv, staging straight from f32 clone ------------
// (verified R2 kernel, unchanged)
__global__ __launch_bounds__(256, 2) void k1_conv(const float* __restrict__ clone,
                                                  const bf16* __restrict__ wpk,
                                                  bf16* __restrict__ cext) {
    const int Xt = blockIdx.x;   // 0..4
    const int Yt = blockIdx.y;   // 0..42  (43*6 = 258 exactly)
    const int b  = blockIdx.z;
    const int t  = threadIdx.x;
    const int L  = t & 63;
    const int wv = t >> 6;
    const int mpair = wv >> 1;
    const int npair = wv & 1;

    extern __shared__ bf16 tile[];       // [8 rows][68 cols][c pitch 72]

    bf16x8 afrag[2][9][2];
    #pragma unroll
    for (int mt = 0; mt < 2; mt++)
        #pragma unroll
        for (int tap = 0; tap < 9; tap++)
            #pragma unroll
            for (int kc = 0; kc < 2; kc++) {
                int idx = ((tap * 2 + kc) * 4 + (mpair * 2 + mt)) * 64 + L;
                afrag[mt][tap][kc] = *(const bf16x8*)(wpk + idx * 8);
            }

    for (int u = t; u < 2176; u += 256) {
        int xq = u % 17;
        int rc = u / 17;
        int cg = rc & 15;
        int r  = rc >> 4;
        int y  = Yt * 6 - 2 + r;
        int xg0 = Xt * 64 - 4 + xq * 4;
        int c0 = cg * 4;
        f32x4 f[4];
        bool yin = (y >= 0) && (y < HH);
        if (yin && xg0 >= 0 && xg0 + 3 < WW) {
            #pragma unroll
            for (int i = 0; i < 4; i++)
                f[i] = *(const f32x4*)(clone + ((size_t)(b * NC + c0 + i) * HH + y) * WW + xg0);
        } else {
            #pragma unroll
            for (int i = 0; i < 4; i++)
                #pragma unroll
                for (int e = 0; e < 4; e++) {
                    int xg = xg0 + e;
                    f[i][e] = (yin && xg >= 0 && xg < WW)
                            ? clone[((size_t)(b * NC + c0 + i) * HH + y) * WW + xg] : 0.0f;
                }
        }
        #pragma unroll
        for (int e = 0; e < 4; e++) {
            bf16x4 h;
            #pragma unroll
            for (int i = 0; i < 4; i++) h[i] = (bf16)f[i][e];
            *(bf16x4*)(tile + (r * 68 + xq * 4 + e) * 72 + c0) = h;
        }
    }
    __syncthreads();

    const int nbase = Xt * 64 + npair * 32;
    const f32x4 zero4 = {0.0f, 0.0f, 0.0f, 0.0f};
    for (int Yi = 0; Yi < 6; Yi++) {
        f32x4 acc[2][2];
        acc[0][0] = zero4; acc[0][1] = zero4; acc[1][0] = zero4; acc[1][1] = zero4;
        #pragma unroll
        for (int tap = 0; tap < 9; tap++) {
            const int ky = tap / 3 - 1;
            const int kx = tap % 3 - 1;
            const int r = Yi + 1 + ky;
            #pragma unroll
            for (int kc = 0; kc < 2; kc++) {
                const int cb = kc * 32 + (L >> 4) * 8;
                #pragma unroll
                for (int nt = 0; nt < 2; nt++) {
                    if (nbase + nt * 16 < EX) {   // wave-uniform skip of dead N-tiles
                        const int col = npair * 32 + nt * 16 + (L & 15) + kx + 3;
                        bf16x8 bfrag = *(const bf16x8*)(tile + (r * 68 + col) * 72 + cb);
                        #pragma unroll
                        for (int mt = 0; mt < 2; mt++)
                            acc[mt][nt] = __builtin_amdgcn_mfma_f32_16x16x32_bf16(
                                afrag[mt][tap][kc], bfrag, acc[mt][nt], 0, 0, 0);
                    }
                }
            }
        }
        int Yp = Yt * 6 + Yi;
        #pragma unroll
        for (int mt = 0; mt < 2; mt++)
            #pragma unroll
            for (int nt = 0; nt < 2; nt++) {
                int Xp = Xt * 64 + npair * 32 + nt * 16 + (L & 15);
                if (Xp < EX) {
                    int o = mpair * 32 + mt * 16 + (L >> 4) * 4;
                    bf16x4 st;
                    #pragma unroll
                    for (int rg = 0; rg < 4; rg++) st[rg] = (bf16)acc[mt][nt][rg];
                    *(bf16x4*)(cext + ((((size_t)b * EX + Yp) * EX + Xp) << 6) + o) = st;
                }
            }
    }
}

// ---------------- K2: fused gather + dots (kvT dense stores; verified R5) --
__global__ __launch_bounds__(256) void k2_gd(const float* __restrict__ uu,
                                             const float* __restrict__ vv,
                                             const float* __restrict__ x,
                                             const bf16* __restrict__ cext,
                                             bf16* __restrict__ kvT,
                                             float* __restrict__ accums) {
    const int bx = blockIdx.x;                    // 0..511
    const int b  = blockIdx.z;
    const int strip = (bx & 7) * 64 + (bx >> 3);  // bijective (512 % 8 == 0)
    const int t = threadIdx.x;
    const int px = t >> 1;
    const int half = t & 1;
    const int hw = strip * 128 + px;
    const int idx = b * NS + hw;
    const int hy = hw >> 8;
    const int wx = hw & 255;

    __shared__ bf16 tile[128][68];                // [s_local][ch], pitch 68

    // ---- gather phase ----
    float fv = vv[idx];
    float fu = uu[idx];
    float py_f = (float)hy + fv;
    float px_f = (float)wx + fu;
    float fy = floorf(py_f);
    float fx = floorf(px_f);
    float ay = py_f - fy;
    float ax = px_f - fx;
    int ys = (int)fy + 1;
    int xs = (int)fx + 1;
    float w00 = (1.0f - ay) * (1.0f - ax);
    float w01 = (1.0f - ay) * ax;
    float w10 = ay * (1.0f - ax);
    float w11 = ay * ax;
    bool y0i = (ys >= 0) && (ys < EX);
    bool y1i = (ys + 1 >= 0) && (ys + 1 < EX);
    bool x0i = (xs >= 0) && (xs < EX);
    bool x1i = (xs + 1 >= 0) && (xs + 1 < EX);
    if (!y0i) { w00 = 0.0f; w01 = 0.0f; }
    if (!y1i) { w10 = 0.0f; w11 = 0.0f; }
    if (!x0i) { w00 = 0.0f; w10 = 0.0f; }
    if (!x1i) { w01 = 0.0f; w11 = 0.0f; }
    int y0c = ys < 0 ? 0 : (ys > EX - 1 ? EX - 1 : ys);
    int y1c = ys + 1 < 0 ? 0 : (ys + 1 > EX - 1 ? EX - 1 : ys + 1);
    int x0c = xs < 0 ? 0 : (xs > EX - 1 ? EX - 1 : xs);
    int x1c = xs + 1 < 0 ? 0 : (xs + 1 > EX - 1 ? EX - 1 : xs + 1);
    const bf16* pb = cext + (((size_t)b * EX * EX) << 6);
    size_t i00 = ((size_t)(y0c * EX + x0c)) << 6;
    size_t i01 = ((size_t)(y0c * EX + x1c)) << 6;
    size_t i10 = ((size_t)(y1c * EX + x0c)) << 6;
    size_t i11 = ((size_t)(y1c * EX + x1c)) << 6;
    const int c0 = half * 32;
    bf16* kvp = kvT + ((size_t)(b * NS + hw)) * 64 + c0;   // 16B-aligned
    #pragma unroll
    for (int g = 0; g < 4; g++) {
        int cg = c0 + g * 8;
        bf16x8 c00 = *(const bf16x8*)(pb + i00 + cg);
        bf16x8 c01 = *(const bf16x8*)(pb + i01 + cg);
        bf16x8 c10 = *(const bf16x8*)(pb + i10 + cg);
        bf16x8 c11 = *(const bf16x8*)(pb + i11 + cg);
        bf16x4 lo, hi;
        bf16x8 sv;
        #pragma unroll
        for (int j = 0; j < 8; j++) {
            float val = w00 * (float)c00[j] + w01 * (float)c01[j]
                      + w10 * (float)c10[j] + w11 * (float)c11[j];
            bf16 hv = (bf16)val;
            sv[j] = hv;
            if (j < 4) lo[j] = hv; else hi[j - 4] = hv;
        }
        *(bf16x8*)(kvp + g * 8) = sv;                      // dense 16B store
        *(bf16x4*)(&tile[px][cg])     = lo;
        *(bf16x4*)(&tile[px][cg + 4]) = hi;
    }
    __syncthreads();

    // ---- dots phase: wave = head ----
    const int L  = t & 63;
    const int h  = t >> 6;
    const int row = L & 15;
    const int kg  = L >> 4;
    const int bh = b * NHEAD + h;
    const float* qb = x + ((size_t)(b * NC + h * DH + row)) * NS + strip * 128;
    f32x4 acc = {0.0f, 0.0f, 0.0f, 0.0f};
    float qp = 0.0f, kp = 0.0f;
    #pragma unroll
    for (int it = 0; it < 4; it++) {
        const int s = it * 32 + kg * 8;
        f32x4 q0 = *(const f32x4*)(qb + s);
        f32x4 q1 = *(const f32x4*)(qb + s + 4);
        bf16x8 qa, ka;
        #pragma unroll
        for (int j = 0; j < 4; j++) {
            qa[j]     = (bf16)q0[j];
            qa[j + 4] = (bf16)q1[j];
        }
        #pragma unroll
        for (int j = 0; j < 8; j++) ka[j] = tile[s + j][h * DH + row];
        qp += q0[0]*q0[0] + q0[1]*q0[1] + q0[2]*q0[2] + q0[3]*q0[3]
            + q1[0]*q1[0] + q1[1]*q1[1] + q1[2]*q1[2] + q1[3]*q1[3];
        #pragma unroll
        for (int j = 0; j < 8; j++) {
            float kf = (float)ka[j];
            kp += kf * kf;
        }
        acc = __builtin_amdgcn_mfma_f32_16x16x32_bf16(qa, ka, acc, 0, 0, 0);
    }
    float* astripe = accums + (bx & 7) * ACCSZ;
    #pragma unroll
    for (int rg = 0; rg < 4; rg++)
        atomicAdd(astripe + bh * 256 + (kg * 4 + rg) * 16 + row, acc[rg]);
    qp += __shfl_xor(qp, 16); qp += __shfl_xor(qp, 32);
    kp += __shfl_xor(kp, 16); kp += __shfl_xor(kp, 32);
    if (kg == 0) {
        atomicAdd(astripe + 2048 + bh * 16 + row, qp);
        atomicAdd(astripe + 2176 + bh * 16 + row, kp);
    }
}

// ---------------- K5: softmax (redundant per block) + out = attn @ kv ------
// R2's verified structure: grid (64,4,2), thread = 4 px x 16 ch of one head.
// Only change vs R2: kv loads come from kvT [b][s][c] as 8x 16 B instead of
// 16x 8 B column-major. FMA loop, softmax, out stores byte-identical to R2.
__global__ __launch_bounds__(256) void k5_out(const bf16* __restrict__ kvT,
                                              const float* __restrict__ accums,
                                              const float* __restrict__ temp,
                                              float* __restrict__ out) {
    const int ci = blockIdx.x;  // 0..63 (1024 s per block)
    const int h  = blockIdx.y;
    const int b  = blockIdx.z;
    const int t  = threadIdx.x;
    const int bh = b * NHEAD + h;
    __shared__ float l[256];
    __shared__ float a[256];
    {
        int i = t >> 4, j = t & 15;
        float dsum = 0.0f, q2 = 0.0f, k2 = 0.0f;
        #pragma unroll
        for (int st = 0; st < NSTRIPE; st++) {
            dsum += accums[st * ACCSZ + bh * 256 + t];
            q2   += accums[st * ACCSZ + 2048 + bh * 16 + i];
            k2   += accums[st * ACCSZ + 2176 + bh * 16 + j];
        }
        float qn = fmaxf(sqrtf(q2), 1e-12f);
        float kn = fmaxf(sqrtf(k2), 1e-12f);
        float logit = dsum / (qn * kn) * temp[h];
        l[t] = logit;
        __syncthreads();
        float mx = -1e30f;
        #pragma unroll
        for (int jj = 0; jj < 16; jj++) mx = fmaxf(mx, l[i * 16 + jj]);
        float sum = 0.0f;
        #pragma unroll
        for (int jj = 0; jj < 16; jj++) sum += expf(l[i * 16 + jj] - mx);
        a[t] = expf(logit - mx) / sum;
        __syncthreads();
    }
    const int s = (ci * 256 + t) * 4;
    const bf16* kvb = kvT + ((size_t)(b * NS + s)) * 64 + h * DH;
    f32x4 kf[16];   // kf[j] = channel j over the 4 px (e)
    #pragma unroll
    for (int e = 0; e < 4; e++) {
        bf16x8 k0 = *(const bf16x8*)(kvb + e * 64);
        bf16x8 k1 = *(const bf16x8*)(kvb + e * 64 + 8);
        #pragma unroll
        for (int j = 0; j < 8; j++) {
            kf[j][e]     = (float)k0[j];
            kf[8 + j][e] = (float)k1[j];
        }
    }
    float* ob = out + ((size_t)(b * NC + h * DH)) * NS + s;
    #pragma unroll
    for (int i = 0; i < 16; i++) {
        f32x4 o = {0.0f, 0.0f, 0.0f, 0.0f};
        #pragma unroll
        for (int j = 0; j < 16; j++)
            o += a[i * 16 + j] * kf[j];
        *(f32x4*)(ob + (size_t)i * NS) = o;
    }
}

extern "C" void kernel_launch(void* const* d_in, const int* in_sizes, int n_in,
                              void* d_out, int out_size, void* d_ws, size_t ws_size,
                              hipStream_t stream) {
    const float* clone = (const float*)d_in[0];
    const float* x     = (const float*)d_in[1];
    const float* u     = (const float*)d_in[2];
    const float* v     = (const float*)d_in[3];
    const float* wgt   = (const float*)d_in[4];
    const float* temp  = (const float*)d_in[5];
    float* out = (float*)d_out;

    char* ws = (char*)d_ws;
    bf16*  cext   = (bf16*) (ws + OFF_CEXT);
    bf16*  kvT    = (bf16*) (ws + OFF_KV);
    bf16*  wpk    = (bf16*) (ws + OFF_WPK);
    float* accums = (float*)(ws + OFF_ACC);

    static bool attr_set = false;
    if (!attr_set) {
        hipFuncSetAttribute((const void*)k1_conv,
                            hipFuncAttributeMaxDynamicSharedMemorySize, 78336);
        attr_set = true;
    }

    k0w<<<90, 256, 0, stream>>>(wgt, wpk, accums);
    k1_conv<<<dim3(5, 43, 2), 256, 78336, stream>>>(clone, wpk, cext);
    k2_gd<<<dim3(512, 1, 2), 256, 0, stream>>>(u, v, x, cext, kvT, accums);
    k5_out<<<dim3(64, 4, 2), 256, 0, stream>>>(kvT, accums, temp, out);
}

// Round 8
// 156.564 us; speedup vs baseline: 1.1043x; 1.0083x over previous
//
#include <hip/hip_runtime.h>

typedef __bf16 bf16;
typedef __bf16 bf16x4 __attribute__((ext_vector_type(4)));
typedef __bf16 bf16x8 __attribute__((ext_vector_type(8)));
typedef float  f32x2  __attribute__((ext_vector_type(2)));
typedef float  f32x4  __attribute__((ext_vector_type(4)));

#define HH 256
#define WW 256
#define NB 2
#define NC 64
#define NS 65536
#define EX 258      // extended conv grid: real coords -1..256, stored +1
#define NHEAD 4
#define DH 16
#define NSTRIPE 8
#define ACCSZ 2304  // per stripe: dots 2048 + qss 128 + kss 128

// ws layout (bytes)
#define OFF_CEXT   0ul                 // 2*258*258*64*2 = 17040384
#define OFF_KV     17040384ul          // kvT [b][s][c] bf16: 2*65536*64*2 = 16777216
#define OFF_WPK    33817600ul          // 73728
#define OFF_ACC    33891328ul          // 8*2304*4 = 73728

// ---------------- K0w: pack weights to A-frag layout + zero accums ---------
__global__ void k0w(const float* __restrict__ wgt, bf16* __restrict__ wpk,
                    float* __restrict__ accums) {
    int t = blockIdx.x * 256 + threadIdx.x;
    if (t < 9 * 2 * 4 * 64) {
        int L   = t & 63;
        int mtg = (t >> 6) & 3;
        int kc  = (t >> 8) & 1;
        int tap = t >> 9;
        int o  = mtg * 16 + (L & 15);
        int cb = kc * 32 + (L >> 4) * 8;
        bf16x8 vv;
        #pragma unroll
        for (int j = 0; j < 8; j++)
            vv[j] = (bf16)wgt[(o * 64 + (cb + j)) * 9 + tap];
        *(bf16x8*)(wpk + t * 8) = vv;
    }
    int z = t - 9 * 2 * 4 * 64;
    if (z >= 0 && z < NSTRIPE * ACCSZ) accums[z] = 0.0f;
}

// ---------------- K1: 3x3 conv, staging straight from f32 clone ------------
// (verified R2 kernel, unchanged)
__global__ __launch_bounds__(256, 2) void k1_conv(const float* __restrict__ clone,
                                                  const bf16* __restrict__ wpk,
                                                  bf16* __restrict__ cext) {
    const int Xt = blockIdx.x;   // 0..4
    const int Yt = blockIdx.y;   // 0..42  (43*6 = 258 exactly)
    const int b  = blockIdx.z;
    const int t  = threadIdx.x;
    const int L  = t & 63;
    const int wv = t >> 6;
    const int mpair = wv >> 1;
    const int npair = wv & 1;

    extern __shared__ bf16 tile[];       // [8 rows][68 cols][c pitch 72]

    bf16x8 afrag[2][9][2];
    #pragma unroll
    for (int mt = 0; mt < 2; mt++)
        #pragma unroll
        for (int tap = 0; tap < 9; tap++)
            #pragma unroll
            for (int kc = 0; kc < 2; kc++) {
                int idx = ((tap * 2 + kc) * 4 + (mpair * 2 + mt)) * 64 + L;
                afrag[mt][tap][kc] = *(const bf16x8*)(wpk + idx * 8);
            }

    for (int u = t; u < 2176; u += 256) {
        int xq = u % 17;
        int rc = u / 17;
        int cg = rc & 15;
        int r  = rc >> 4;
        int y  = Yt * 6 - 2 + r;
        int xg0 = Xt * 64 - 4 + xq * 4;
        int c0 = cg * 4;
        f32x4 f[4];
        bool yin = (y >= 0) && (y < HH);
        if (yin && xg0 >= 0 && xg0 + 3 < WW) {
            #pragma unroll
            for (int i = 0; i < 4; i++)
                f[i] = *(const f32x4*)(clone + ((size_t)(b * NC + c0 + i) * HH + y) * WW + xg0);
        } else {
            #pragma unroll
            for (int i = 0; i < 4; i++)
                #pragma unroll
                for (int e = 0; e < 4; e++) {
                    int xg = xg0 + e;
                    f[i][e] = (yin && xg >= 0 && xg < WW)
                            ? clone[((size_t)(b * NC + c0 + i) * HH + y) * WW + xg] : 0.0f;
                }
        }
        #pragma unroll
        for (int e = 0; e < 4; e++) {
            bf16x4 h;
            #pragma unroll
            for (int i = 0; i < 4; i++) h[i] = (bf16)f[i][e];
            *(bf16x4*)(tile + (r * 68 + xq * 4 + e) * 72 + c0) = h;
        }
    }
    __syncthreads();

    const int nbase = Xt * 64 + npair * 32;
    const f32x4 zero4 = {0.0f, 0.0f, 0.0f, 0.0f};
    for (int Yi = 0; Yi < 6; Yi++) {
        f32x4 acc[2][2];
        acc[0][0] = zero4; acc[0][1] = zero4; acc[1][0] = zero4; acc[1][1] = zero4;
        #pragma unroll
        for (int tap = 0; tap < 9; tap++) {
            const int ky = tap / 3 - 1;
            const int kx = tap % 3 - 1;
            const int r = Yi + 1 + ky;
            #pragma unroll
            for (int kc = 0; kc < 2; kc++) {
                const int cb = kc * 32 + (L >> 4) * 8;
                #pragma unroll
                for (int nt = 0; nt < 2; nt++) {
                    if (nbase + nt * 16 < EX) {   // wave-uniform skip of dead N-tiles
                        const int col = npair * 32 + nt * 16 + (L & 15) + kx + 3;
                        bf16x8 bfrag = *(const bf16x8*)(tile + (r * 68 + col) * 72 + cb);
                        #pragma unroll
                        for (int mt = 0; mt < 2; mt++)
                            acc[mt][nt] = __builtin_amdgcn_mfma_f32_16x16x32_bf16(
                                afrag[mt][tap][kc], bfrag, acc[mt][nt], 0, 0, 0);
                    }
                }
            }
        }
        int Yp = Yt * 6 + Yi;
        #pragma unroll
        for (int mt = 0; mt < 2; mt++)
            #pragma unroll
            for (int nt = 0; nt < 2; nt++) {
                int Xp = Xt * 64 + npair * 32 + nt * 16 + (L & 15);
                if (Xp < EX) {
                    int o = mpair * 32 + mt * 16 + (L >> 4) * 4;
                    bf16x4 st;
                    #pragma unroll
                    for (int rg = 0; rg < 4; rg++) st[rg] = (bf16)acc[mt][nt][rg];
                    *(bf16x4*)(cext + ((((size_t)b * EX + Yp) * EX + Xp) << 6) + o) = st;
                }
            }
    }
}

// ---------------- K2: fused gather + dots, 64-px strips for 2x TLP ---------
// 2048 blocks (8/CU candidate residency); thread = 1 px x 16 ch.
// Same verified gather algebra, LDS tile, wave=head dots, striped atomics.
__global__ __launch_bounds__(256) void k2_gd(const float* __restrict__ uu,
                                             const float* __restrict__ vv,
                                             const float* __restrict__ x,
                                             const bf16* __restrict__ cext,
                                             bf16* __restrict__ kvT,
                                             float* __restrict__ accums) {
    const int bx = blockIdx.x;                     // 0..1023
    const int b  = blockIdx.z;
    const int strip = (bx & 7) * 128 + (bx >> 3);  // bijective (1024 % 8 == 0)
    const int t = threadIdx.x;
    const int px = t >> 2;                         // 0..63
    const int q4 = t & 3;
    const int hw = strip * 64 + px;
    const int idx = b * NS + hw;
    const int hy = hw >> 8;
    const int wx = hw & 255;

    __shared__ bf16 tile[64][68];                  // [s_local][ch], pitch 68

    // ---- gather phase (verified algebra) ----
    float fv = vv[idx];
    float fu = uu[idx];
    float py_f = (float)hy + fv;
    float px_f = (float)wx + fu;
    float fy = floorf(py_f);
    float fx = floorf(px_f);
    float ay = py_f - fy;
    float ax = px_f - fx;
    int ys = (int)fy + 1;
    int xs = (int)fx + 1;
    float w00 = (1.0f - ay) * (1.0f - ax);
    float w01 = (1.0f - ay) * ax;
    float w10 = ay * (1.0f - ax);
    float w11 = ay * ax;
    bool y0i = (ys >= 0) && (ys < EX);
    bool y1i = (ys + 1 >= 0) && (ys + 1 < EX);
    bool x0i = (xs >= 0) && (xs < EX);
    bool x1i = (xs + 1 >= 0) && (xs + 1 < EX);
    if (!y0i) { w00 = 0.0f; w01 = 0.0f; }
    if (!y1i) { w10 = 0.0f; w11 = 0.0f; }
    if (!x0i) { w00 = 0.0f; w10 = 0.0f; }
    if (!x1i) { w01 = 0.0f; w11 = 0.0f; }
    int y0c = ys < 0 ? 0 : (ys > EX - 1 ? EX - 1 : ys);
    int y1c = ys + 1 < 0 ? 0 : (ys + 1 > EX - 1 ? EX - 1 : ys + 1);
    int x0c = xs < 0 ? 0 : (xs > EX - 1 ? EX - 1 : xs);
    int x1c = xs + 1 < 0 ? 0 : (xs + 1 > EX - 1 ? EX - 1 : xs + 1);
    const bf16* pb = cext + (((size_t)b * EX * EX) << 6);
    size_t i00 = ((size_t)(y0c * EX + x0c)) << 6;
    size_t i01 = ((size_t)(y0c * EX + x1c)) << 6;
    size_t i10 = ((size_t)(y1c * EX + x0c)) << 6;
    size_t i11 = ((size_t)(y1c * EX + x1c)) << 6;
    const int c0 = q4 * 16;
    bf16* kvp = kvT + ((size_t)(b * NS + hw)) * 64 + c0;   // 16B-aligned
    #pragma unroll
    for (int g = 0; g < 2; g++) {
        int cg = c0 + g * 8;
        bf16x8 c00 = *(const bf16x8*)(pb + i00 + cg);
        bf16x8 c01 = *(const bf16x8*)(pb + i01 + cg);
        bf16x8 c10 = *(const bf16x8*)(pb + i10 + cg);
        bf16x8 c11 = *(const bf16x8*)(pb + i11 + cg);
        bf16x4 lo, hi;
        bf16x8 sv;
        #pragma unroll
        for (int j = 0; j < 8; j++) {
            float val = w00 * (float)c00[j] + w01 * (float)c01[j]
                      + w10 * (float)c10[j] + w11 * (float)c11[j];
            bf16 hv = (bf16)val;
            sv[j] = hv;
            if (j < 4) lo[j] = hv; else hi[j - 4] = hv;
        }
        *(bf16x8*)(kvp + g * 8) = sv;                      // dense 16B store
        *(bf16x4*)(&tile[px][cg])     = lo;
        *(bf16x4*)(&tile[px][cg + 4]) = hi;
    }
    __syncthreads();

    // ---- dots phase: wave = head (2 MFMA k-iters over 64 s) ----
    const int L  = t & 63;
    const int h  = t >> 6;
    const int row = L & 15;
    const int kg  = L >> 4;
    const int bh = b * NHEAD + h;
    const float* qb = x + ((size_t)(b * NC + h * DH + row)) * NS + strip * 64;
    f32x4 acc = {0.0f, 0.0f, 0.0f, 0.0f};
    float qp = 0.0f, kp = 0.0f;
    #pragma unroll
    for (int it = 0; it < 2; it++) {
        const int s = it * 32 + kg * 8;
        f32x4 q0 = *(const f32x4*)(qb + s);
        f32x4 q1 = *(const f32x4*)(qb + s + 4);
        bf16x8 qa, ka;
        #pragma unroll
        for (int j = 0; j < 4; j++) {
            qa[j]     = (bf16)q0[j];
            qa[j + 4] = (bf16)q1[j];
        }
        #pragma unroll
        for (int j = 0; j < 8; j++) ka[j] = tile[s + j][h * DH + row];
        qp += q0[0]*q0[0] + q0[1]*q0[1] + q0[2]*q0[2] + q0[3]*q0[3]
            + q1[0]*q1[0] + q1[1]*q1[1] + q1[2]*q1[2] + q1[3]*q1[3];
        #pragma unroll
        for (int j = 0; j < 8; j++) {
            float kf = (float)ka[j];
            kp += kf * kf;
        }
        acc = __builtin_amdgcn_mfma_f32_16x16x32_bf16(qa, ka, acc, 0, 0, 0);
    }
    float* astripe = accums + (bx & 7) * ACCSZ;
    #pragma unroll
    for (int rg = 0; rg < 4; rg++)
        atomicAdd(astripe + bh * 256 + (kg * 4 + rg) * 16 + row, acc[rg]);
    qp += __shfl_xor(qp, 16); qp += __shfl_xor(qp, 32);
    kp += __shfl_xor(kp, 16); kp += __shfl_xor(kp, 32);
    if (kg == 0) {
        atomicAdd(astripe + 2048 + bh * 16 + row, qp);
        atomicAdd(astripe + 2176 + bh * 16 + row, kp);
    }
}

// ---------------- K5: softmax (redundant per block) + out = attn @ kv ------
// 2 px per thread -> 1024 blocks x 4 waves = 16 waves/CU (2x TLP vs R7).
// Softmax block byte-identical to verified R2; FMA loop in f32x2.
__global__ __launch_bounds__(256) void k5_out(const bf16* __restrict__ kvT,
                                              const float* __restrict__ accums,
                                              const float* __restrict__ temp,
                                              float* __restrict__ out) {
    const int ci = blockIdx.x;  // 0..127 (512 s per block)
    const int h  = blockIdx.y;
    const int b  = blockIdx.z;
    const int t  = threadIdx.x;
    const int bh = b * NHEAD + h;
    __shared__ float l[256];
    __shared__ float a[256];
    {
        int i = t >> 4, j = t & 15;
        float dsum = 0.0f, q2 = 0.0f, k2 = 0.0f;
        #pragma unroll
        for (int st = 0; st < NSTRIPE; st++) {
            dsum += accums[st * ACCSZ + bh * 256 + t];
            q2   += accums[st * ACCSZ + 2048 + bh * 16 + i];
            k2   += accums[st * ACCSZ + 2176 + bh * 16 + j];
        }
        float qn = fmaxf(sqrtf(q2), 1e-12f);
        float kn = fmaxf(sqrtf(k2), 1e-12f);
        float logit = dsum / (qn * kn) * temp[h];
        l[t] = logit;
        __syncthreads();
        float mx = -1e30f;
        #pragma unroll
        for (int jj = 0; jj < 16; jj++) mx = fmaxf(mx, l[i * 16 + jj]);
        float sum = 0.0f;
        #pragma unroll
        for (int jj = 0; jj < 16; jj++) sum += expf(l[i * 16 + jj] - mx);
        a[t] = expf(logit - mx) / sum;
        __syncthreads();
    }
    const int s = (ci * 256 + t) * 2;
    const bf16* kvb = kvT + ((size_t)(b * NS + s)) * 64 + h * DH;
    f32x2 kf[16];   // kf[j] = channel j over the 2 px (e)
    #pragma unroll
    for (int e = 0; e < 2; e++) {
        bf16x8 k0 = *(const bf16x8*)(kvb + e * 64);
        bf16x8 k1 = *(const bf16x8*)(kvb + e * 64 + 8);
        #pragma unroll
        for (int j = 0; j < 8; j++) {
            kf[j][e]     = (float)k0[j];
            kf[8 + j][e] = (float)k1[j];
        }
    }
    float* ob = out + ((size_t)(b * NC + h * DH)) * NS + s;
    #pragma unroll
    for (int i = 0; i < 16; i++) {
        f32x2 o = {0.0f, 0.0f};
        #pragma unroll
        for (int j = 0; j < 16; j++)
            o += a[i * 16 + j] * kf[j];
        *(f32x2*)(ob + (size_t)i * NS) = o;
    }
}

extern "C" void kernel_launch(void* const* d_in, const int* in_sizes, int n_in,
                              void* d_out, int out_size, void* d_ws, size_t ws_size,
                              hipStream_t stream) {
    const float* clone = (const float*)d_in[0];
    const float* x     = (const float*)d_in[1];
    const float* u     = (const float*)d_in[2];
    const float* v     = (const float*)d_in[3];
    const float* wgt   = (const float*)d_in[4];
    const float* temp  = (const float*)d_in[5];
    float* out = (float*)d_out;

    char* ws = (char*)d_ws;
    bf16*  cext   = (bf16*) (ws + OFF_CEXT);
    bf16*  kvT    = (bf16*) (ws + OFF_KV);
    bf16*  wpk    = (bf16*) (ws + OFF_WPK);
    float* accums = (float*)(ws + OFF_ACC);

    static bool attr_set = false;
    if (!attr_set) {
        hipFuncSetAttribute((const void*)k1_conv,
                            hipFuncAttributeMaxDynamicSharedMemorySize, 78336);
        attr_set = true;
    }

    k0w<<<90, 256, 0, stream>>>(wgt, wpk, accums);
    k1_conv<<<dim3(5, 43, 2), 256, 78336, stream>>>(clone, wpk, cext);
    k2_gd<<<dim3(1024, 1, 2), 256, 0, stream>>>(u, v, x, cext, kvT, accums);
    k5_out<<<dim3(128, 4, 2), 256, 0, stream>>>(kvT, accums, temp, out);
}